// Round 5
// baseline (185.214 us; speedup 1.0000x reference)
//
#include <hip/hip_runtime.h>

#define KK 8
#define DD 16
#define NN 32
#define TT 200
#define BB 2048

// C and A live in LDS as packed bf16 (u32 = 2 elems). Per-k slab strides in
// u32 units are == 4 (mod 32) so the 8 distinct per-lane states land on 8
// distinct 4-bank groups covering all 32 banks -> conflict-free ds_read_b128.
#define SCU 260  // C slab stride in u32 (256 used = 512 bf16)
#define SAU 132  // A slab stride in u32 (128 used = 256 bf16)
#define SE 36    // emission fp32 table stride (32 used)
#define SD 20    // dyn/init fp32 table stride (16 used)

__device__ __forceinline__ float bflo(unsigned u) { return __uint_as_float(u << 16); }
__device__ __forceinline__ float bfhi(unsigned u) { return __uint_as_float(u & 0xffff0000u); }

// round-to-nearest bf16
__device__ __forceinline__ unsigned bfr(float f) {
  unsigned u = __float_as_uint(f);
  return (u + 0x7fffu + ((u >> 16) & 1u)) >> 16;
}
__device__ __forceinline__ unsigned bfpack(float f0, float f1) {
  return bfr(f0) | (bfr(f1) << 16);
}

// dot of a 16-elem bf16-packed row (8 u32, two uint4 LDS reads) with fp32 z
__device__ __forceinline__ float dot16bf(const unsigned* __restrict__ row,
                                         const float* __restrict__ z) {
  uint4 w0 = *reinterpret_cast<const uint4*>(row);
  uint4 w1 = *reinterpret_cast<const uint4*>(row + 4);
  float a = bflo(w0.x) * z[0], b = bfhi(w0.x) * z[1];
  a = fmaf(bflo(w0.y), z[2], a);  b = fmaf(bfhi(w0.y), z[3], b);
  a = fmaf(bflo(w0.z), z[4], a);  b = fmaf(bfhi(w0.z), z[5], b);
  a = fmaf(bflo(w0.w), z[6], a);  b = fmaf(bfhi(w0.w), z[7], b);
  a = fmaf(bflo(w1.x), z[8], a);  b = fmaf(bfhi(w1.x), z[9], b);
  a = fmaf(bflo(w1.y), z[10], a); b = fmaf(bfhi(w1.y), z[11], b);
  a = fmaf(bflo(w1.z), z[12], a); b = fmaf(bfhi(w1.z), z[13], b);
  a = fmaf(bflo(w1.w), z[14], a); b = fmaf(bfhi(w1.w), z[15], b);
  return a + b;
}

// No min-waves clause (R2's forced 128-VGPR cap spilled -> core dump under
// graph capture). Emission register pressure is capped by sched_barrier(0)
// between groups (R1 evidence: unconstrained full unroll -> 256 VGPR + spill).
__global__ __launch_bounds__(256) void slds_lp_kernel(
    const int* __restrict__ dsts,      // [B,T]
    const float* __restrict__ zg,      // [B,T,D]
    const float* __restrict__ obsg,    // [B,T,N]
    const float* __restrict__ initlg,  // [K]
    const float* __restrict__ initloc, // [K,D]
    const float* __restrict__ initls,  // [K,D]
    const float* __restrict__ transg,  // [K,K]
    const float* __restrict__ Ag,      // [K,D,D]
    const float* __restrict__ dynoff,  // [K,D]
    const float* __restrict__ dynls,   // [K,D] (scale directly, NOT log)
    const float* __restrict__ Cg,      // [K,N,D]
    const float* __restrict__ emoff,   // [K,N]
    const float* __restrict__ emls,    // [K,N]
    float* __restrict__ out)           // [B]
{
  __shared__ __align__(16) unsigned sCu[KK * SCU];   // 8320 B, bf16 packed
  __shared__ __align__(16) unsigned sAu[KK * SAU];   // 4224 B, bf16 packed
  __shared__ __align__(16) float sEmOff[KK * SE];
  __shared__ __align__(16) float sEmInv[KK * SE];
  __shared__ __align__(16) float sDynOff[KK * SD];
  __shared__ __align__(16) float sDynInv[KK * SD];
  __shared__ __align__(16) float sInitLoc[KK * SD];
  __shared__ __align__(16) float sInitInv[KK * SD];
  __shared__ float sTrans[KK * KK];
  __shared__ float sEmConst[KK];
  __shared__ float sDynConst[KK];
  __shared__ float sInitLp[KK];

  const float HALF_LOG2PI = 0.91893853320467274178f;
  const int tid = threadIdx.x;

  // ---- stage params into LDS (transform + bf16 quantize once per block) ----
  for (int i = tid; i < KK * NN * DD / 2; i += 256) {   // 2048 u32
    int k = i >> 8, r = i & 255;
    sCu[k * SCU + r] = bfpack(Cg[2 * i], Cg[2 * i + 1]);
  }
  for (int i = tid; i < KK * DD * DD / 2; i += 256) {   // 1024 u32
    int k = i >> 7, r = i & 127;
    sAu[k * SAU + r] = bfpack(Ag[2 * i], Ag[2 * i + 1]);
  }
  if (tid < KK * NN) {                                  // 256
    int k = tid >> 5, n = tid & 31;
    sEmOff[k * SE + n] = emoff[tid];
    sEmInv[k * SE + n] = expf(-emls[tid]);
  }
  if (tid < KK * DD) {                                  // 128
    int k = tid >> 4, d = tid & 15;
    sDynOff[k * SD + d] = dynoff[tid];
    sDynInv[k * SD + d] = 1.0f / dynls[tid];
    sInitLoc[k * SD + d] = initloc[tid];
    sInitInv[k * SD + d] = expf(-initls[tid]);
  }
  if (tid < KK * KK) {                                  // 64: trans log-softmax
    int kr = tid >> 3;
    float mx = transg[kr * KK];
    for (int j = 1; j < KK; ++j) mx = fmaxf(mx, transg[kr * KK + j]);
    float ss = 0.f;
    for (int j = 0; j < KK; ++j) ss += expf(transg[kr * KK + j] - mx);
    sTrans[tid] = transg[tid] - (logf(ss) + mx);
  }
  if (tid < KK) {                                       // per-k constants
    int k = tid;
    float se = 0.f;
    for (int n = 0; n < NN; ++n) se -= emls[k * NN + n];
    sEmConst[k] = se - NN * HALF_LOG2PI;
    float sd = 0.f;
    for (int d = 0; d < DD; ++d) sd -= logf(dynls[k * DD + d]);
    sDynConst[k] = sd - DD * HALF_LOG2PI;
    float mx = initlg[0];
    for (int j = 1; j < KK; ++j) mx = fmaxf(mx, initlg[j]);
    float ss = 0.f;
    for (int j = 0; j < KK; ++j) ss += expf(initlg[j] - mx);
    float si = 0.f;
    for (int d = 0; d < DD; ++d) si -= initls[k * DD + d];
    sInitLp[k] = initlg[k] - (logf(ss) + mx) + si - DD * HALF_LOG2PI;
  }
  __syncthreads();

  // ---- one thread per (b,t) item ----
  const int nItems = BB * TT;
  const int gstride = gridDim.x * blockDim.x;
  for (int item = blockIdx.x * blockDim.x + tid; item < nItems; item += gstride) {
    const int b = item / TT;
    const int t = item - b * TT;

    // ---- hoisted global loads: ONE batched vmcnt chain (obs, z, states) ----
    const float4* o4 = reinterpret_cast<const float4*>(obsg + (size_t)item * NN);
    float4 o0 = o4[0], o1 = o4[1], o2 = o4[2], o3 = o4[3];
    float4 o5_0 = o4[4], o5_1 = o4[5], o5_2 = o4[6], o5_3 = o4[7];
    float zz[16];
    {
      const float4* p = reinterpret_cast<const float4*>(zg + (size_t)item * DD);
      float4 a0 = p[0], a1 = p[1], a2 = p[2], a3 = p[3];
      zz[0] = a0.x; zz[1] = a0.y; zz[2] = a0.z; zz[3] = a0.w;
      zz[4] = a1.x; zz[5] = a1.y; zz[6] = a1.z; zz[7] = a1.w;
      zz[8] = a2.x; zz[9] = a2.y; zz[10] = a2.z; zz[11] = a2.w;
      zz[12] = a3.x; zz[13] = a3.y; zz[14] = a3.z; zz[15] = a3.w;
    }
    const int s = dsts[item];
    const int sp = dsts[(t != 0) ? (item - 1) : item];  // clamped; unused at t==0

    const int cb = s * SCU;
    const int eb4 = s * (SE / 4);
    float acc0 = 0.f, acc1 = 0.f;

#define EMG(g, ov, accv) do {                                              \
    float4 off = reinterpret_cast<const float4*>(sEmOff)[eb4 + (g)];       \
    float4 inv = reinterpret_cast<const float4*>(sEmInv)[eb4 + (g)];       \
    float l0 = dot16bf(&sCu[cb + ((g) * 4 + 0) * 8], zz) + off.x;          \
    float l1 = dot16bf(&sCu[cb + ((g) * 4 + 1) * 8], zz) + off.y;          \
    float l2 = dot16bf(&sCu[cb + ((g) * 4 + 2) * 8], zz) + off.z;          \
    float l3 = dot16bf(&sCu[cb + ((g) * 4 + 3) * 8], zz) + off.w;          \
    float d0 = (ov.x - l0) * inv.x;                                        \
    float d1 = (ov.y - l1) * inv.y;                                        \
    float d2 = (ov.z - l2) * inv.z;                                        \
    float d3 = (ov.w - l3) * inv.w;                                        \
    accv = fmaf(d0, d0, accv); accv = fmaf(d1, d1, accv);                  \
    accv = fmaf(d2, d2, accv); accv = fmaf(d3, d3, accv);                  \
  } while (0)

    // Fully unrolled (constant indices) with sched_barrier(0) between groups:
    // caps live LDS rows at ~1 group while keeping the hoisted global loads
    // in the first scheduling region (can't sink across a barrier).
    EMG(0, o0, acc0);   __builtin_amdgcn_sched_barrier(0);
    EMG(1, o1, acc1);   __builtin_amdgcn_sched_barrier(0);
    EMG(2, o2, acc0);   __builtin_amdgcn_sched_barrier(0);
    EMG(3, o3, acc1);   __builtin_amdgcn_sched_barrier(0);
    EMG(4, o5_0, acc0); __builtin_amdgcn_sched_barrier(0);
    EMG(5, o5_1, acc1); __builtin_amdgcn_sched_barrier(0);
    EMG(6, o5_2, acc0); __builtin_amdgcn_sched_barrier(0);
    EMG(7, o5_3, acc1);
#undef EMG

    float lp = -0.5f * (acc0 + acc1) + sEmConst[s];

    if (t != 0) {
      float zp[16];
      {
        const float4* p = reinterpret_cast<const float4*>(zg + (size_t)(item - 1) * DD);
        float4 a0 = p[0], a1 = p[1], a2 = p[2], a3 = p[3];
        zp[0] = a0.x; zp[1] = a0.y; zp[2] = a0.z; zp[3] = a0.w;
        zp[4] = a1.x; zp[5] = a1.y; zp[6] = a1.z; zp[7] = a1.w;
        zp[8] = a2.x; zp[9] = a2.y; zp[10] = a2.z; zp[11] = a2.w;
        zp[12] = a3.x; zp[13] = a3.y; zp[14] = a3.z; zp[15] = a3.w;
      }
      const int ab = s * SAU;
      const int db4 = s * (SD / 4);
      float a2acc = 0.f;
#pragma unroll 2
      for (int g = 0; g < 4; ++g) {
        float4 off = reinterpret_cast<const float4*>(sDynOff)[db4 + g];
        float4 inv = reinterpret_cast<const float4*>(sDynInv)[db4 + g];
        int i0 = g * 4;
        float l0 = dot16bf(&sAu[ab + (i0 + 0) * 8], zp) + off.x;
        float l1 = dot16bf(&sAu[ab + (i0 + 1) * 8], zp) + off.y;
        float l2 = dot16bf(&sAu[ab + (i0 + 2) * 8], zp) + off.z;
        float l3 = dot16bf(&sAu[ab + (i0 + 3) * 8], zp) + off.w;
        float d0 = (zz[i0 + 0] - l0) * inv.x;
        float d1 = (zz[i0 + 1] - l1) * inv.y;
        float d2 = (zz[i0 + 2] - l2) * inv.z;
        float d3 = (zz[i0 + 3] - l3) * inv.w;
        a2acc = fmaf(d0, d0, a2acc); a2acc = fmaf(d1, d1, a2acc);
        a2acc = fmaf(d2, d2, a2acc); a2acc = fmaf(d3, d3, a2acc);
      }
      lp += -0.5f * a2acc + sDynConst[s] + sTrans[sp * KK + s];
    } else {
      const int ib4 = s * (SD / 4);
      float a2acc = 0.f;
#pragma unroll 2
      for (int g = 0; g < 4; ++g) {
        float4 loc = reinterpret_cast<const float4*>(sInitLoc)[ib4 + g];
        float4 inv = reinterpret_cast<const float4*>(sInitInv)[ib4 + g];
        int i0 = g * 4;
        float d0 = (zz[i0 + 0] - loc.x) * inv.x;
        float d1 = (zz[i0 + 1] - loc.y) * inv.y;
        float d2 = (zz[i0 + 2] - loc.z) * inv.z;
        float d3 = (zz[i0 + 3] - loc.w) * inv.w;
        a2acc = fmaf(d0, d0, a2acc); a2acc = fmaf(d1, d1, a2acc);
        a2acc = fmaf(d2, d2, a2acc); a2acc = fmaf(d3, d3, a2acc);
      }
      lp += -0.5f * a2acc + sInitLp[s];
    }

    // ---- wave-level segmented sum keyed by b (<=2 segments/wave), then atomic
    const int lane = tid & 63;
    float v = lp;
#pragma unroll
    for (int off = 1; off < 64; off <<= 1) {
      float ov = __shfl_up(v, off, 64);
      int obk = __shfl_up(b, off, 64);
      if (lane >= off && obk == b) v += ov;
    }
    int nb = __shfl_down(b, 1, 64);
    if (lane == 63 || nb != b) atomicAdd(&out[b], v);
  }
}

extern "C" void kernel_launch(void* const* d_in, const int* in_sizes, int n_in,
                              void* d_out, int out_size, void* d_ws, size_t ws_size,
                              hipStream_t stream) {
  const int*   dsts    = (const int*)d_in[0];
  const float* zg      = (const float*)d_in[1];
  const float* obsg    = (const float*)d_in[2];
  const float* initlg  = (const float*)d_in[3];
  const float* initloc = (const float*)d_in[4];
  const float* initls  = (const float*)d_in[5];
  const float* transg  = (const float*)d_in[6];
  const float* Ag      = (const float*)d_in[7];
  const float* dynoff  = (const float*)d_in[8];
  const float* dynls   = (const float*)d_in[9];
  const float* Cg      = (const float*)d_in[10];
  const float* emoff   = (const float*)d_in[11];
  const float* emls    = (const float*)d_in[12];
  float* out = (float*)d_out;

  hipMemsetAsync(d_out, 0, BB * sizeof(float), stream);

  // 1600 blocks x 256 threads == exactly B*T items, one per thread
  slds_lp_kernel<<<1600, 256, 0, stream>>>(dsts, zg, obsg, initlg, initloc,
                                           initls, transg, Ag, dynoff, dynls,
                                           Cg, emoff, emls, out);
}

// Round 6
// 144.828 us; speedup vs baseline: 1.2789x; 1.2789x over previous
//
#include <hip/hip_runtime.h>

#define KK 8
#define DD 16
#define NN 32
#define TT 200
#define BB 2048

// C and A live in LDS as packed bf16 (u32 = 2 elems). Per-k slab strides in
// u32 units are == 4 (mod 32) so the 8 distinct per-lane states land on 8
// distinct 4-bank groups covering all 32 banks -> conflict-free ds_read_b128.
#define SCU 260  // C slab stride in u32 (256 used = 512 bf16)
#define SAU 132  // A slab stride in u32 (128 used = 256 bf16)
#define SE 36    // emission fp32 table stride (32 used)
#define SD 20    // dyn/init fp32 table stride (16 used)

// d_ws layout (32-bit units)
#define WS_CU    0      // 2048 u32 packed bf16 C
#define WS_AU    2048   // 1024 u32 packed bf16 A
#define WS_EMOFF 3072   // 256 f32
#define WS_EMINV 3328   // 256 f32
#define WS_DYOFF 3584   // 128 f32
#define WS_DYINV 3712   // 128 f32
#define WS_INLOC 3840   // 128 f32
#define WS_ININV 3968   // 128 f32
#define WS_TRANS 4096   // 64 f32
#define WS_EMC   4160   // 8 f32
#define WS_DYC   4168   // 8 f32
#define WS_INLP  4176   // 8 f32

__device__ __forceinline__ float bflo(unsigned u) { return __uint_as_float(u << 16); }
__device__ __forceinline__ float bfhi(unsigned u) { return __uint_as_float(u & 0xffff0000u); }

__device__ __forceinline__ unsigned bfr(float f) {  // RN bf16
  unsigned u = __float_as_uint(f);
  return (u + 0x7fffu + ((u >> 16) & 1u)) >> 16;
}
__device__ __forceinline__ unsigned bfpack(float f0, float f1) {
  return bfr(f0) | (bfr(f1) << 16);
}

// dot of a 16-elem bf16-packed row (8 u32, two uint4 LDS reads) with fp32 z
__device__ __forceinline__ float dot16bf(const unsigned* __restrict__ row,
                                         const float* __restrict__ z) {
  uint4 w0 = *reinterpret_cast<const uint4*>(row);
  uint4 w1 = *reinterpret_cast<const uint4*>(row + 4);
  float a = bflo(w0.x) * z[0], b = bfhi(w0.x) * z[1];
  a = fmaf(bflo(w0.y), z[2], a);  b = fmaf(bfhi(w0.y), z[3], b);
  a = fmaf(bflo(w0.z), z[4], a);  b = fmaf(bfhi(w0.z), z[5], b);
  a = fmaf(bflo(w0.w), z[6], a);  b = fmaf(bfhi(w0.w), z[7], b);
  a = fmaf(bflo(w1.x), z[8], a);  b = fmaf(bfhi(w1.x), z[9], b);
  a = fmaf(bflo(w1.y), z[10], a); b = fmaf(bfhi(w1.y), z[11], b);
  a = fmaf(bflo(w1.z), z[12], a); b = fmaf(bfhi(w1.z), z[13], b);
  a = fmaf(bflo(w1.w), z[14], a); b = fmaf(bfhi(w1.w), z[15], b);
  return a + b;
}

// -------- prep: runs ONCE per launch (1 block). Packs C/A to bf16, applies
// all transcendental transforms, zeroes out[]. Removes the per-block
// transcendental prologue that serialized every main-kernel block (R4
// evidence: VALUBusy 40% / occ 35% with all pipes idle -> prologue+latency).
__global__ __launch_bounds__(256) void prep_kernel(
    const float* __restrict__ initlg, const float* __restrict__ initloc,
    const float* __restrict__ initls, const float* __restrict__ transg,
    const float* __restrict__ Ag, const float* __restrict__ dynoff,
    const float* __restrict__ dynls, const float* __restrict__ Cg,
    const float* __restrict__ emoff, const float* __restrict__ emls,
    unsigned* __restrict__ ws, float* __restrict__ out) {
  const float HALF_LOG2PI = 0.91893853320467274178f;
  const int tid = threadIdx.x;
  float* wsf = reinterpret_cast<float*>(ws);

  for (int i = tid; i < 2048; i += 256)
    ws[WS_CU + i] = bfpack(Cg[2 * i], Cg[2 * i + 1]);
  for (int i = tid; i < 1024; i += 256)
    ws[WS_AU + i] = bfpack(Ag[2 * i], Ag[2 * i + 1]);
  if (tid < 256) { wsf[WS_EMOFF + tid] = emoff[tid]; wsf[WS_EMINV + tid] = expf(-emls[tid]); }
  if (tid < 128) {
    wsf[WS_DYOFF + tid] = dynoff[tid];
    wsf[WS_DYINV + tid] = 1.0f / dynls[tid];
    wsf[WS_INLOC + tid] = initloc[tid];
    wsf[WS_ININV + tid] = expf(-initls[tid]);
  }
  if (tid < 64) {
    int kr = tid >> 3;
    float mx = transg[kr * KK];
    for (int j = 1; j < KK; ++j) mx = fmaxf(mx, transg[kr * KK + j]);
    float ss = 0.f;
    for (int j = 0; j < KK; ++j) ss += expf(transg[kr * KK + j] - mx);
    wsf[WS_TRANS + tid] = transg[tid] - (logf(ss) + mx);
  }
  if (tid < 8) {
    int k = tid;
    float se = 0.f;
    for (int n = 0; n < NN; ++n) se -= emls[k * NN + n];
    wsf[WS_EMC + k] = se - NN * HALF_LOG2PI;
    float sd = 0.f;
    for (int d = 0; d < DD; ++d) sd -= logf(dynls[k * DD + d]);
    wsf[WS_DYC + k] = sd - DD * HALF_LOG2PI;
    float mx = initlg[0];
    for (int j = 1; j < KK; ++j) mx = fmaxf(mx, initlg[j]);
    float ss = 0.f;
    for (int j = 0; j < KK; ++j) ss += expf(initlg[j] - mx);
    float si = 0.f;
    for (int d = 0; d < DD; ++d) si -= initls[k * DD + d];
    wsf[WS_INLP + k] = initlg[k] - (logf(ss) + mx) + si - DD * HALF_LOG2PI;
  }
  for (int i = tid; i < BB; i += 256) out[i] = 0.f;  // replaces memset dispatch
}

// No min-waves clause (R2: forced 128-VGPR cap spilled -> core dump under
// graph capture). No sched_barrier (R5: 220 VGPR, 82us). Pressure controlled
// by "#pragma unroll 2" (R4: 44 VGPR, the best inner loop so far).
__global__ __launch_bounds__(256) void slds_lp_kernel(
    const int* __restrict__ dsts,      // [B,T]
    const float* __restrict__ zg,      // [B,T,D]
    const float* __restrict__ obsg,    // [B,T,N]
    const unsigned* __restrict__ ws,   // prep output
    float* __restrict__ out)           // [B]
{
  __shared__ __align__(16) unsigned sCu[KK * SCU];
  __shared__ __align__(16) unsigned sAu[KK * SAU];
  __shared__ __align__(16) float sEmOff[KK * SE];
  __shared__ __align__(16) float sEmInv[KK * SE];
  __shared__ __align__(16) float sDynOff[KK * SD];
  __shared__ __align__(16) float sDynInv[KK * SD];
  __shared__ __align__(16) float sInitLoc[KK * SD];
  __shared__ __align__(16) float sInitInv[KK * SD];
  __shared__ float sTrans[KK * KK];
  __shared__ float sEmConst[KK];
  __shared__ float sDynConst[KK];
  __shared__ float sInitLp[KK];

  const int tid = threadIdx.x;
  const float* wsf = reinterpret_cast<const float*>(ws);

  // ---- stage prepacked params: pure coalesced copies, no math, L2-hot ----
  for (int i = tid; i < 2048; i += 256) {
    int k = i >> 8, r = i & 255;
    sCu[k * SCU + r] = ws[WS_CU + i];
  }
  for (int i = tid; i < 1024; i += 256) {
    int k = i >> 7, r = i & 127;
    sAu[k * SAU + r] = ws[WS_AU + i];
  }
  if (tid < 256) {
    int k = tid >> 5, n = tid & 31;
    sEmOff[k * SE + n] = wsf[WS_EMOFF + tid];
    sEmInv[k * SE + n] = wsf[WS_EMINV + tid];
  }
  if (tid < 128) {
    int k = tid >> 4, d = tid & 15;
    sDynOff[k * SD + d] = wsf[WS_DYOFF + tid];
    sDynInv[k * SD + d] = wsf[WS_DYINV + tid];
    sInitLoc[k * SD + d] = wsf[WS_INLOC + tid];
    sInitInv[k * SD + d] = wsf[WS_ININV + tid];
  }
  if (tid < 64) sTrans[tid] = wsf[WS_TRANS + tid];
  if (tid < 8) {
    sEmConst[tid] = wsf[WS_EMC + tid];
    sDynConst[tid] = wsf[WS_DYC + tid];
    sInitLp[tid] = wsf[WS_INLP + tid];
  }
  __syncthreads();

  // ---- one thread per (b,t) item ----
  const int nItems = BB * TT;
  const int gstride = gridDim.x * blockDim.x;
  for (int item = blockIdx.x * blockDim.x + tid; item < nItems; item += gstride) {
    const int b = item / TT;
    const int t = item - b * TT;
    const int lane = tid & 63;

    float zz[16];
    {
      const float4* p = reinterpret_cast<const float4*>(zg + (size_t)item * DD);
      float4 a0 = p[0], a1 = p[1], a2 = p[2], a3 = p[3];
      zz[0] = a0.x; zz[1] = a0.y; zz[2] = a0.z; zz[3] = a0.w;
      zz[4] = a1.x; zz[5] = a1.y; zz[6] = a1.z; zz[7] = a1.w;
      zz[8] = a2.x; zz[9] = a2.y; zz[10] = a2.z; zz[11] = a2.w;
      zz[12] = a3.x; zz[13] = a3.y; zz[14] = a3.z; zz[15] = a3.w;
    }
    const int s = dsts[item];

    // zp/sp are the previous lane's zz/s (items are lane-consecutive):
    // shuffle instead of dependent global loads. Lane 0 falls back to global.
    float zpg[4];  // lane-0 fallback staged as float4s below
    float zp[16];
    int sp = __shfl_up(s, 1, 64);
    if (lane == 0 && t != 0) {
      sp = dsts[item - 1];
      const float4* p = reinterpret_cast<const float4*>(zg + (size_t)(item - 1) * DD);
      float4 a0 = p[0], a1 = p[1], a2 = p[2], a3 = p[3];
      zp[0] = a0.x; zp[1] = a0.y; zp[2] = a0.z; zp[3] = a0.w;
      zp[4] = a1.x; zp[5] = a1.y; zp[6] = a1.z; zp[7] = a1.w;
      zp[8] = a2.x; zp[9] = a2.y; zp[10] = a2.z; zp[11] = a2.w;
      zp[12] = a3.x; zp[13] = a3.y; zp[14] = a3.z; zp[15] = a3.w;
    }
#pragma unroll
    for (int i = 0; i < 16; ++i) {
      float sh = __shfl_up(zz[i], 1, 64);
      if (lane != 0) zp[i] = sh;
    }
    (void)zpg;

    // ---- emissions: R4's proven unroll-2 loop ----
    const float4* o4 = reinterpret_cast<const float4*>(obsg + (size_t)item * NN);
    const int cb = s * SCU;
    const int eb4 = s * (SE / 4);
    float acc = 0.f;
#pragma unroll 2
    for (int g = 0; g < 8; ++g) {
      float4 o = o4[g];
      float4 off = reinterpret_cast<const float4*>(sEmOff)[eb4 + g];
      float4 inv = reinterpret_cast<const float4*>(sEmInv)[eb4 + g];
      int n0 = g * 4;
      float l0 = dot16bf(&sCu[cb + (n0 + 0) * 8], zz) + off.x;
      float l1 = dot16bf(&sCu[cb + (n0 + 1) * 8], zz) + off.y;
      float l2 = dot16bf(&sCu[cb + (n0 + 2) * 8], zz) + off.z;
      float l3 = dot16bf(&sCu[cb + (n0 + 3) * 8], zz) + off.w;
      float d0 = (o.x - l0) * inv.x;
      float d1 = (o.y - l1) * inv.y;
      float d2 = (o.z - l2) * inv.z;
      float d3 = (o.w - l3) * inv.w;
      acc = fmaf(d0, d0, acc); acc = fmaf(d1, d1, acc);
      acc = fmaf(d2, d2, acc); acc = fmaf(d3, d3, acc);
    }
    float lp = -0.5f * acc + sEmConst[s];

    if (t != 0) {
      const int ab = s * SAU;
      const int db4 = s * (SD / 4);
      float a2acc = 0.f;
#pragma unroll 2
      for (int g = 0; g < 4; ++g) {
        float4 off = reinterpret_cast<const float4*>(sDynOff)[db4 + g];
        float4 inv = reinterpret_cast<const float4*>(sDynInv)[db4 + g];
        int i0 = g * 4;
        float l0 = dot16bf(&sAu[ab + (i0 + 0) * 8], zp) + off.x;
        float l1 = dot16bf(&sAu[ab + (i0 + 1) * 8], zp) + off.y;
        float l2 = dot16bf(&sAu[ab + (i0 + 2) * 8], zp) + off.z;
        float l3 = dot16bf(&sAu[ab + (i0 + 3) * 8], zp) + off.w;
        float d0 = (zz[i0 + 0] - l0) * inv.x;
        float d1 = (zz[i0 + 1] - l1) * inv.y;
        float d2 = (zz[i0 + 2] - l2) * inv.z;
        float d3 = (zz[i0 + 3] - l3) * inv.w;
        a2acc = fmaf(d0, d0, a2acc); a2acc = fmaf(d1, d1, a2acc);
        a2acc = fmaf(d2, d2, a2acc); a2acc = fmaf(d3, d3, a2acc);
      }
      lp += -0.5f * a2acc + sDynConst[s] + sTrans[sp * KK + s];
    } else {
      const int ib4 = s * (SD / 4);
      float a2acc = 0.f;
#pragma unroll 2
      for (int g = 0; g < 4; ++g) {
        float4 loc = reinterpret_cast<const float4*>(sInitLoc)[ib4 + g];
        float4 inv = reinterpret_cast<const float4*>(sInitInv)[ib4 + g];
        int i0 = g * 4;
        float d0 = (zz[i0 + 0] - loc.x) * inv.x;
        float d1 = (zz[i0 + 1] - loc.y) * inv.y;
        float d2 = (zz[i0 + 2] - loc.z) * inv.z;
        float d3 = (zz[i0 + 3] - loc.w) * inv.w;
        a2acc = fmaf(d0, d0, a2acc); a2acc = fmaf(d1, d1, a2acc);
        a2acc = fmaf(d2, d2, a2acc); a2acc = fmaf(d3, d3, a2acc);
      }
      lp += -0.5f * a2acc + sInitLp[s];
    }

    // ---- wave-level segmented sum keyed by b (<=2 segments/wave), then atomic
    float v = lp;
#pragma unroll
    for (int off = 1; off < 64; off <<= 1) {
      float ov = __shfl_up(v, off, 64);
      int obk = __shfl_up(b, off, 64);
      if (lane >= off && obk == b) v += ov;
    }
    int nb = __shfl_down(b, 1, 64);
    if (lane == 63 || nb != b) atomicAdd(&out[b], v);
  }
}

extern "C" void kernel_launch(void* const* d_in, const int* in_sizes, int n_in,
                              void* d_out, int out_size, void* d_ws, size_t ws_size,
                              hipStream_t stream) {
  const int*   dsts    = (const int*)d_in[0];
  const float* zg      = (const float*)d_in[1];
  const float* obsg    = (const float*)d_in[2];
  const float* initlg  = (const float*)d_in[3];
  const float* initloc = (const float*)d_in[4];
  const float* initls  = (const float*)d_in[5];
  const float* transg  = (const float*)d_in[6];
  const float* Ag      = (const float*)d_in[7];
  const float* dynoff  = (const float*)d_in[8];
  const float* dynls   = (const float*)d_in[9];
  const float* Cg      = (const float*)d_in[10];
  const float* emoff   = (const float*)d_in[11];
  const float* emls    = (const float*)d_in[12];
  float* out = (float*)d_out;
  unsigned* ws = (unsigned*)d_ws;

  // prep (1 block): packs params + tables into ws, zeroes out[].
  prep_kernel<<<1, 256, 0, stream>>>(initlg, initloc, initls, transg, Ag,
                                     dynoff, dynls, Cg, emoff, emls, ws, out);
  // main: 1600 x 256 == exactly B*T items, one per thread
  slds_lp_kernel<<<1600, 256, 0, stream>>>(dsts, zg, obsg, ws, out);
}